// Round 12
// baseline (322.938 us; speedup 1.0000x reference)
//
#include <hip/hip_runtime.h>
#include <hip/hip_bf16.h>
#include <cstddef>

// Problem constants
constexpr int B = 2, L = 2048, D = 2048;
constexpr int H = 16, HKV = 4, HD = 128;
constexpr int GROUPS = H / HKV;          // 4
constexpr int KVD = 2 * HKV * HD;        // 1024
constexpr int M_ROWS = B * L;            // 4096
constexpr int QKVW = D + KVD;            // 3072 fused qkv width

typedef __attribute__((ext_vector_type(8))) short short8;   // 8 bf16 (4 VGPRs)
typedef __attribute__((ext_vector_type(4))) short s16x4;    // 4 bf16 (8B)
typedef __attribute__((ext_vector_type(4))) float f32x4;    // MFMA C/D

__device__ __forceinline__ short f2bf(float f) {
    union { float f; unsigned u; } v; v.f = f;
    unsigned r = v.u + 0x7FFFu + ((v.u >> 16) & 1u);   // RNE
    return (short)(r >> 16);
}

__device__ __forceinline__ float fast_exp2(float x) {
#if __has_builtin(__builtin_amdgcn_exp2f)
    return __builtin_amdgcn_exp2f(x);      // single v_exp_f32
#else
    return exp2f(x);
#endif
}

// RoPE-friendly in-head feature permutation:
// forward pi(d) = (d%16) + 32*(d/16)          (d < 64)
//              = (d%16) + 32*((d-64)/16) + 16 (d >= 64)
// => pair (i, i+64) sits at positions (p, p+16): same thread's nt/nt+1 slots.
// inverse (position pos -> original feature d):
__device__ __forceinline__ int invp(int pos) {
    const int b16 = pos >> 4, j = pos & 15;
    return ((b16 >> 1) << 4) + j + ((b16 & 1) << 6);
}

typedef __attribute__((address_space(1))) const void cg_void;
typedef __attribute__((address_space(3))) void lds_void;
__device__ __forceinline__ void gl_lds16(const void* g, void* l) {
    // async global->LDS: per-lane global gather, LDS dest = wave base + lane*16
    __builtin_amdgcn_global_load_lds((cg_void*)g, (lds_void*)l, 16, 0, 0);
}

// ---------------- fused fp32 -> bf16 casts + bias concat (one launch) ----------------
__global__ __launch_bounds__(256) void cast_all(
    const float* __restrict__ x, const float* __restrict__ Wq,
    const float* __restrict__ Wkv, const float* __restrict__ Wo,
    const float* __restrict__ bq, const float* __restrict__ bkv,
    short* __restrict__ xb, short* __restrict__ wqkvb, short* __restrict__ wob,
    float* __restrict__ bqkv)
{
    constexpr int n_x   = M_ROWS * D / 4;    // 2097152
    constexpr int n_wq  = D * D / 4;         // 1048576
    constexpr int n_wkv = KVD * D / 4;       // 524288
    constexpr int n_wo  = D * D / 4;         // 1048576
    constexpr int n_w   = n_x + n_wq + n_wkv + n_wo;   // 4718592
    constexpr int RPW   = D / 4;             // 512 float4 per weight row
    int i = blockIdx.x * 256 + threadIdx.x;
    if (i >= n_w) {
        const int j = i - n_w;               // [0, 768): bias float4
        float4 o;
#pragma unroll
        for (int e = 0; e < 4; ++e) {
            const int idx = j * 4 + e;
            float v;
            if (idx < D)                 v = bq[((idx >> 7) << 7) + invp(idx & 127)];
            else if (idx < D + HKV * HD) v = bkv[(((idx - D) >> 7) << 7) + invp((idx - D) & 127)];
            else                         v = bkv[idx - D];
            (&o.x)[e] = v;
        }
        ((float4*)bqkv)[j] = o;
        return;
    }
    const float* src; short* dst; int isrc;
    if (i < n_x) {
        src = x; dst = xb; isrc = i;
    } else if (i < n_x + n_wq) {
        i -= n_x; src = Wq; dst = wqkvb;
        const int fi = i / RPW, col = i % RPW;
        const int head = fi >> 7, pos = fi & 127;
        isrc = ((head << 7) + invp(pos)) * RPW + col;
    } else if (i < n_x + n_wq + n_wkv) {
        i -= n_x + n_wq; src = Wkv; dst = wqkvb + (size_t)D * D;
        const int fi = i / RPW, col = i % RPW;
        if (fi < HKV * HD) {      // k rows: permuted gather
            isrc = (((fi >> 7) << 7) + invp(fi & 127)) * RPW + col;
        } else {                  // v rows: identity
            isrc = i;
        }
    } else {
        i -= n_x + n_wq + n_wkv; src = Wo; dst = wob; isrc = i;
    }
    const float4 f = ((const float4*)src)[isrc];
    s16x4 s;
    s[0] = f2bf(f.x); s[1] = f2bf(f.y); s[2] = f2bf(f.z); s[3] = f2bf(f.w);
    ((s16x4*)dst)[i] = s;
}

// ---------------- 128x128 bf16 MFMA GEMM (m97 structure + swizzle) ----------------
// 256 threads = 4 waves (2x2); wave tile 64x64; BK=32; LDS 16KB single-buffer
// (As+Bs) inside a 32KB block (epilogue tile overlay). VGPR ~80-100 => 3-5
// co-resident blocks/CU: inter-block wave overlap hides the per-step barrier
// drain (m114/m97: this structure = 912 TF at 128^2, beats 1-block/CU 256^2).
// Bank-conflict fix: granule ^= (row>>1)&3 applied on the GLOBAL source col
// (linear LDS dest, rule #21) and on the frag-read address (8-way -> 2-way=free).
// MODE 0: C = acc + bias (fp32), output projection.
// MODE 1: fused qkv epilogue (bias + RoPE via permuted basis; LDS-staged
//         coalesced writeout; v tiles transposed to vt[b][hkv][d][l]).
template<int MODE>
__global__ __launch_bounds__(256) void gemm128(
    const short* __restrict__ Ag, const short* __restrict__ Wg,
    const float* __restrict__ bias, float* __restrict__ C,
    const float* __restrict__ cosp, const float* __restrict__ sinp,
    short* __restrict__ qout, short* __restrict__ kout, short* __restrict__ vtout,
    int M, int N, int K)
{
    __shared__ __align__(1024) char smem[32768];
    short* const As = (short*)smem;             // [128*32]
    short* const Bs = (short*)(smem + 8192);    // [128*32]

    const int tid = threadIdx.x;
    const int w = tid >> 6, lane = tid & 63;
    const int quad = lane >> 4, n16 = lane & 15;
    const int wm = (w & 1) * 64, wn = (w >> 1) * 64;

    // bijective XCD-aware swizzle (768 and 512 blocks: both % 8 == 0)
    const int nbx = gridDim.x;
    const int nwg = nbx * gridDim.y;
    int wg = blockIdx.y * nbx + blockIdx.x;
    wg = (wg & 7) * (nwg >> 3) + (wg >> 3);
    const int bm = (wg / nbx) << 7;
    const int bn = (wg % nbx) << 7;

    // staging lane constants: lane l fills LDS row l>>2, granule l&3 (8 elems);
    // source granule pre-swizzled by row bits [2:1]  (both-sides-or-neither)
    const int sr = lane >> 2;
    const int sc = (((lane & 3) ^ ((lane >> 3) & 3)) * 8);

    // frag-read granule swizzle: slot = quad ^ (row bits [2:1]) ; row%8 == n16%8
    const int rsw = ((n16 >> 1) & 3);

    f32x4 acc[4][4];
#pragma unroll
    for (int i = 0; i < 4; ++i)
#pragma unroll
        for (int j = 0; j < 4; ++j)
#pragma unroll
            for (int r = 0; r < 4; ++r) acc[i][j][r] = 0.f;

    for (int k0 = 0; k0 < K; k0 += 32) {
#pragma unroll
        for (int it = 0; it < 2; ++it) {
            const int row0 = it * 64 + w * 16;
            gl_lds16(Ag + (size_t)(bm + row0 + sr) * K + k0 + sc, &As[row0 * 32]);
            gl_lds16(Wg + (size_t)(bn + row0 + sr) * K + k0 + sc, &Bs[row0 * 32]);
        }
        __syncthreads();

        short8 af[4], bf[4];
#pragma unroll
        for (int mt = 0; mt < 4; ++mt)
            af[mt] = *(const short8*)&As[(wm + mt * 16 + n16) * 32 + ((quad ^ rsw) * 8)];
#pragma unroll
        for (int nt = 0; nt < 4; ++nt)
            bf[nt] = *(const short8*)&Bs[(wn + nt * 16 + n16) * 32 + ((quad ^ rsw) * 8)];
        __builtin_amdgcn_s_setprio(1);
#pragma unroll
        for (int mt = 0; mt < 4; ++mt)
#pragma unroll
            for (int nt = 0; nt < 4; ++nt)
                acc[mt][nt] = __builtin_amdgcn_mfma_f32_16x16x32_bf16(
                    af[mt], bf[nt], acc[mt][nt], 0, 0, 0);
        __builtin_amdgcn_s_setprio(0);
        __syncthreads();
    }

    if (MODE == 0) {
        // ---- plain epilogue: C = acc + bias (fp32)
#pragma unroll
        for (int mt = 0; mt < 4; ++mt)
#pragma unroll
            for (int r = 0; r < 4; ++r) {
                const int row = bm + wm + mt * 16 + quad * 4 + r;
#pragma unroll
                for (int nt = 0; nt < 4; ++nt) {
                    const int col = bn + wn + nt * 16 + n16;
                    C[(size_t)row * N + col] = acc[mt][nt][r] + bias[col];
                }
            }
    } else {
        // ---- fused qkv epilogue: stage the 128x128 bf16 tile T in the (dead)
        // 32KB smem, then coalesced short8 writeout.
        short* const T = (short*)smem;
        __syncthreads();
        if (bn < D + HKV * HD) {
            // -- q (bn<2048) / k (2048<=bn<2560): bias + RoPE -> T[row][col]
            // pairs sit in nt/nt+1 slots (cols cl, cl+16); original feature
            // i = n16 + (wn>>1) + ntp*16, hi partner at i+64.
#pragma unroll
            for (int mt = 0; mt < 4; ++mt)
#pragma unroll
                for (int r = 0; r < 4; ++r) {
                    const int rl = wm + mt * 16 + quad * 4 + r;
                    const int row = bm + rl;
                    const float* csrow = cosp + (size_t)row * HD;
                    const float* snrow = sinp + (size_t)row * HD;
                    const int sw = ((rl >> 2) & 7) << 4;   // byte-XOR bank swizzle
#pragma unroll
                    for (int ntp = 0; ntp < 2; ++ntp) {
                        const int cl = wn + ntp * 32 + n16;
                        const int iif = n16 + (wn >> 1) + ntp * 16;
                        const float a  = acc[mt][2 * ntp + 0][r] + bias[bn + cl];
                        const float bb = acc[mt][2 * ntp + 1][r] + bias[bn + cl + 16];
                        const float olo = a * csrow[iif]       - bb * snrow[iif];
                        const float ohi = bb * csrow[iif + 64] + a * snrow[iif + 64];
                        *(short*)((char*)T + ((rl * 256 + cl * 2) ^ sw))        = f2bf(olo);
                        *(short*)((char*)T + ((rl * 256 + (cl + 16) * 2) ^ sw)) = f2bf(ohi);
                    }
                }
            __syncthreads();
            const bool isK = (bn >= D);
#pragma unroll
            for (int it = 0; it < 8; ++it) {
                const int idx = it * 256 + tid;
                const int rl = idx >> 4, c8 = idx & 15;
                const short8 v = *(const short8*)((char*)T +
                    ((rl * 256 + c8 * 16) ^ (((rl >> 2) & 7) << 4)));
                const int row = bm + rl;
                if (!isK) {
                    *(short8*)&qout[(size_t)row * D + bn + c8 * 8] = v;
                } else {
                    const int hk = (bn - D) >> 7;          // each k tile = one head
                    const int b_ = row >> 11, l_ = row & (L - 1);
                    *(short8*)&kout[((size_t)(b_ * HKV + hk) * L + l_) * HD + c8 * 8] = v;
                }
            }
        } else {
            // -- v: bias + cast -> T[cv][l] (transpose in LDS)
#pragma unroll
            for (int mt = 0; mt < 4; ++mt) {
                const int l0 = wm + mt * 16 + quad * 4;
#pragma unroll
                for (int nt = 0; nt < 4; ++nt) {
                    const int cl = wn + nt * 16 + n16;
                    const float bs = bias[bn + cl];
                    s16x4 sv;
#pragma unroll
                    for (int r = 0; r < 4; ++r)
                        sv[r] = f2bf(acc[mt][nt][r] + bs);
                    *(s16x4*)((char*)T + ((cl * 256 + l0 * 2) ^ ((cl & 7) << 4))) = sv;
                }
            }
            __syncthreads();
#pragma unroll
            for (int it = 0; it < 8; ++it) {
                const int idx = it * 256 + tid;
                const int cvr = idx >> 4, l8 = idx & 15;
                const short8 v = *(const short8*)((char*)T +
                    ((cvr * 256 + l8 * 16) ^ ((cvr & 7) << 4)));
                const int cv = bn - (D + HKV * HD) + cvr;
                const int hv = cv >> 7, dv = cv & 127;
                const int b_ = bm >> 11;
                const int lg = (bm & (L - 1)) + l8 * 8;
                *(short8*)&vtout[((size_t)(b_ * HKV + hv) * HD + dv) * L + lg] = v;
            }
        }
    }
}

// ---------------- GQA MFMA flash attention, QBLK=16 key-split, 2 blocks/CU ----------------
// Grid = (64, HKV, B) = 512 blocks; block = 8 waves (512 thr). Waves 0-3 =
// 4 q-heads x keys [0,32); waves 4-7 = same heads x keys [32,64). Each block
// does the balanced qidx pair {bx, 127-bx} (16 q-rows each). LDS 75776B +
// __launch_bounds__(512,4) => 2 co-resident blocks/CU. Fixed-max softmax =>
// O/l partials add across key halves; one LDS reduction per phase.
__global__ __launch_bounds__(512, 4) void attn_mfma5(
    const short* __restrict__ qb_, const short* __restrict__ kb_,
    const short* __restrict__ vtb_, short* __restrict__ ob)
{
    // LDS: Ks[2][64*128] (32768B) | Vt[2][128*64] (32768B) | Pb[8][16][40] (10240B)
    // Rbuf overlay (front 4*64*40*4 = 40960B) used only after the post-loop barrier.
    __shared__ __align__(16) char smem[75776];
    short* const KsB  = (short*)smem;             // [2][8192]
    short* const VtB  = (short*)(smem + 32768);   // [2][8192]
    short* const PbB  = (short*)(smem + 65536);   // [8][16][40]
    float* const Rbuf = (float*)smem;             // overlay: [4][64][40]

    const int hkv = blockIdx.y, b = blockIdx.z;
    const int tid = threadIdx.x;
    const int w = tid >> 6, lane = tid & 63;
    const int quad = lane >> 4, n16 = lane & 15;
    const int h   = hkv * GROUPS + (w & 3);  // this wave's q-head
    const int kh  = (w >> 2) * 32;           // key-half offset within the 64-key tile
    const int khg = (w >> 2) * 4;            // granule offset for Vt slot selection

    const size_t kbase  = (size_t)(b * HKV + hkv) * L * HD;
    const size_t vtbase = (size_t)(b * HKV + hkv) * HD * L;
    const float c1 = 0.12751845f;    // (1/sqrt(128)) * log2(e)
    const float c0 = -28.853901f;    // -20 * log2(e)  (fixed-max offset)

    short8 ones;
#pragma unroll
    for (int i = 0; i < 8; ++i) ones[i] = (short)0x3F80;   // bf16 1.0

    // staging lane constants (granule swizzle; 2 K-chunks + 2 V-chunks per wave)
    const int kr = lane >> 4;                // K: row within 4-row chunk
    const int kg_sw = lane & 15;             // K: granule slot
    const int vr = lane >> 3;                // V: row within 8-row chunk
    const int vg_sw = lane & 7;

    short* const myPb = PbB + w * (16 * 40);   // this wave's [16][40]

#pragma unroll 1
    for (int phase = 0; phase < 2; ++phase) {
        const int qidx = phase ? (127 - (int)blockIdx.x) : (int)blockIdx.x;
        const int qb0 = qidx * 16;
        const int ntiles = (qidx >> 2) + 1;

        // Q A-frags: 1 rowtile x 4 ksteps
        short8 qf[4];
#pragma unroll
        for (int kk = 0; kk < 4; ++kk)
            qf[kk] = *(const short8*)&qb_[
                ((size_t)(b * L + qb0 + n16)) * D + h * HD + kk * 32 + quad * 8];

        f32x4 oacc[8], lacc;
#pragma unroll
        for (int r = 0; r < 4; ++r) lacc[r] = 0.f;
#pragma unroll
        for (int nt = 0; nt < 8; ++nt)
#pragma unroll
            for (int r = 0; r < 4; ++r) oacc[nt][r] = 0.f;

        __syncthreads();   // prev phase fully done (incl. Rbuf reads) before staging overlays

        // stage tile 0 -> buf 0 (16 K-chunks + 16 V-chunks split over 8 waves)
        {
            const short* kg = kb_ + kbase;
            const short* vg = vtb_ + vtbase;
#pragma unroll
            for (int j = 0; j < 2; ++j) {
                const int chunk = w * 2 + j;
                const int r = chunk * 4 + kr;
                gl_lds16(kg + r * HD + (kg_sw ^ (r & 15)) * 8, KsB + chunk * 512);
            }
#pragma unroll
            for (int j = 0; j < 2; ++j) {
                const int chunk = w * 2 + j;
                const int d = chunk * 8 + vr;
                gl_lds16(vg + (size_t)d * L + (vg_sw ^ (d & 7)) * 8, VtB + chunk * 512);
            }
        }

        for (int kt = 0; kt < ntiles; ++kt) {
            const int buf = kt & 1;
            __syncthreads();   // drains DMA for tile kt; prev-buf readers done

            // prefetch tile kt+1 into the other buffer (hidden behind compute)
            if (kt + 1 < ntiles) {
                const short* kg = kb_ + kbase + (size_t)((kt + 1) * 64) * HD;
                const short* vg = vtb_ + vtbase + (kt + 1) * 64;
#pragma unroll
                for (int j = 0; j < 2; ++j) {
                    const int chunk = w * 2 + j;
                    const int r = chunk * 4 + kr;
                    gl_lds16(kg + r * HD + (kg_sw ^ (r & 15)) * 8,
                             KsB + (buf ^ 1) * 8192 + chunk * 512);
                }
#pragma unroll
                for (int j = 0; j < 2; ++j) {
                    const int chunk = w * 2 + j;
                    const int d = chunk * 8 + vr;
                    gl_lds16(vg + (size_t)d * L + (vg_sw ^ (d & 7)) * 8,
                             VtB + (buf ^ 1) * 8192 + chunk * 512);
                }
            }

            const short* Ks = KsB + buf * 8192;
            const short* Vt = VtB + buf * 8192;

            // ---- S = Q K^T : 2 keytiles (this wave's key half) x 4 ksteps
            f32x4 s[2];
#pragma unroll
            for (int ktl = 0; ktl < 2; ++ktl)
#pragma unroll
                for (int r = 0; r < 4; ++r) s[ktl][r] = 0.f;
            __builtin_amdgcn_s_setprio(1);
#pragma unroll
            for (int kk = 0; kk < 4; ++kk) {
                short8 kf[2];
#pragma unroll
                for (int ktl = 0; ktl < 2; ++ktl) {
                    const int row = kh + ktl * 16 + n16;
                    kf[ktl] = *(const short8*)&Ks[row * 128 + ((kk * 4 + quad) ^ n16) * 8];
                }
#pragma unroll
                for (int ktl = 0; ktl < 2; ++ktl)
                    s[ktl] = __builtin_amdgcn_mfma_f32_16x16x32_bf16(
                        qf[kk], kf[ktl], s[ktl], 0, 0, 0);
            }
            __builtin_amdgcn_s_setprio(0);

            // ---- fixed-max softmax: e = exp2(s*c1 + c0); mask on last tile
            const bool lastt = (kt == ntiles - 1);
#pragma unroll
            for (int ktl = 0; ktl < 2; ++ktl) {
                const int key0 = kt * 64 + kh + ktl * 16 + n16;
#pragma unroll
                for (int r = 0; r < 4; ++r) {
                    float sv = s[ktl][r];
                    if (lastt) {
                        const int qi = qb0 + quad * 4 + r;
                        sv = (key0 <= qi) ? sv : -1e30f;
                    }
                    const float e = fast_exp2(sv * c1 + c0);
                    myPb[(quad * 4 + r) * 40 + ktl * 16 + n16] = f2bf(e);
                }
            }
            asm volatile("s_waitcnt lgkmcnt(0)" ::: "memory");   // Pb visible (same wave)

            // ---- P A-frag (16x32) + l += P@ones + O += P V(half)
            const short8 pf = *(const short8*)&myPb[n16 * 40 + quad * 8];
            __builtin_amdgcn_s_setprio(1);
            lacc = __builtin_amdgcn_mfma_f32_16x16x32_bf16(pf, ones, lacc, 0, 0, 0);
#pragma unroll
            for (int nt = 0; nt < 8; ++nt) {
                const short8 vf = *(const short8*)&Vt[
                    (nt * 16 + n16) * 64 + ((khg + quad) ^ (n16 & 7)) * 8];
                oacc[nt] = __builtin_amdgcn_mfma_f32_16x16x32_bf16(pf, vf, oacc[nt], 0, 0, 0);
            }
            __builtin_amdgcn_s_setprio(0);
        }

        // ---- cross-half reduction: upper key-half partials -> lower waves
        __syncthreads();                      // all waves done reading Ks/Vt/Pb (overlay safe)
        if (w >= 4) {
            float* rp = Rbuf + ((size_t)(w - 4) * 64 + lane) * 40;
#pragma unroll
            for (int nt = 0; nt < 8; ++nt)
                *(f32x4*)&rp[nt * 4] = oacc[nt];
            *(f32x4*)&rp[32] = lacc;
        }
        __syncthreads();
        if (w < 4) {
            const float* rp = Rbuf + ((size_t)w * 64 + lane) * 40;
            const f32x4 lr = *(const f32x4*)&rp[32];
#pragma unroll
            for (int r = 0; r < 4; ++r) lacc[r] += lr[r];
#pragma unroll
            for (int nt = 0; nt < 8; ++nt) {
                const f32x4 o2 = *(const f32x4*)&rp[nt * 4];
#pragma unroll
                for (int r = 0; r < 4; ++r) oacc[nt][r] += o2[r];
            }
            // ---- finalize: O/l, bf16 out
#pragma unroll
            for (int r = 0; r < 4; ++r) {
                const float inv = 1.0f / lacc[r];
                short* op = ob + ((size_t)(b * L + qb0 + quad * 4 + r)) * D + h * HD + n16;
#pragma unroll
                for (int nt = 0; nt < 8; ++nt) op[nt * 16] = f2bf(oacc[nt][r] * inv);
            }
        }
    }
}

// ---------------- launch ----------------
extern "C" void kernel_launch(void* const* d_in, const int* in_sizes, int n_in,
                              void* d_out, int out_size, void* d_ws, size_t ws_size,
                              hipStream_t stream)
{
    const float* x    = (const float*)d_in[0];
    const float* cosp = (const float*)d_in[1];
    const float* sinp = (const float*)d_in[2];
    const float* Wq   = (const float*)d_in[3];
    const float* bq   = (const float*)d_in[4];
    const float* Wkv  = (const float*)d_in[5];
    const float* bkv  = (const float*)d_in[6];
    const float* Wo   = (const float*)d_in[7];
    const float* bo   = (const float*)d_in[8];
    float* out = (float*)d_out;

    char* p = (char*)d_ws;
    short* x_bf    = (short*)p; p += (size_t)M_ROWS * D * 2;        // 16.8 MB (reused as attn out)
    short* wqkv_bf = (short*)p; p += (size_t)QKVW * D * 2;          // 12.6 MB
    short* wo_bf   = (short*)p; p += (size_t)D * D * 2;             //  8.4 MB
    float* b_qkv   = (float*)p; p += (size_t)QKVW * 4;              //  12 KB
    short* q_bf    = (short*)p; p += (size_t)M_ROWS * D * 2;        // 16.8 MB
    short* k_bf    = (short*)p; p += (size_t)M_ROWS * HKV * HD * 2; //  4.2 MB
    short* vt_bf   = (short*)p;                                     //  4.2 MB
    short* attn_bf = x_bf;   // x_bf dead after qkv GEMM

    dim3 blk(256);

    // fused cast + bias launch: x, Wq(perm), Wkv(k perm), Wo, b_qkv (18435 blocks)
    cast_all<<<dim3(18435), blk, 0, stream>>>(
        x, Wq, Wkv, Wo, bq, bkv, x_bf, wqkv_bf, wo_bf, b_qkv);

    // fused qkv GEMM + bias + RoPE + q/k/vt writes (24x32 = 768 blocks, 3/CU)
    gemm128<1><<<dim3(QKVW / 128, M_ROWS / 128), blk, 0, stream>>>(
        x_bf, wqkv_bf, b_qkv, nullptr, cosp, sinp, q_bf, k_bf, vt_bf,
        M_ROWS, QKVW, D);

    // attention: QBLK=16 pairs, 512 blocks -> 2 co-resident blocks/CU
    attn_mfma5<<<dim3(64, HKV, B), dim3(512), 0, stream>>>(q_bf, k_bf, vt_bf, attn_bf);

    // out = attn @ Wo^T + bo   (16x32 = 512 blocks, 2/CU)
    gemm128<0><<<dim3(D / 128, M_ROWS / 128), blk, 0, stream>>>(
        attn_bf, wo_bf, bo, out, nullptr, nullptr, nullptr, nullptr, nullptr,
        M_ROWS, D, D);
}